// Round 1
// baseline (1179.114 us; speedup 1.0000x reference)
//
#include <hip/hip_runtime.h>
#include <math.h>

#define N_TOK 131072
#define DIM 64
#define KCODES 1024
#define TPB 128        // tokens per block (main kernel)
#define KC 128         // code chunk staged in LDS
#define LROW 132       // padded LDS row stride (floats)
#define TIE_EPS 1e-4f

// ---------------- prep: normalize codebook (transposed), fp64 inv norms, zero counters
__global__ __launch_bounds__(64) void vq_prep(
    const float* __restrict__ w, float* __restrict__ cbT,
    double* __restrict__ inv_n64, int* __restrict__ count, double* __restrict__ accum)
{
    int k = blockIdx.x;
    int d = threadIdx.x;
    float v = w[k * DIM + d];
    float s = v * v;
    #pragma unroll
    for (int off = 32; off; off >>= 1) s += __shfl_xor(s, off);
    float den = fmaxf(sqrtf(s), 1e-12f);
    cbT[d * KCODES + k] = v / den;

    double vd = (double)v;
    double sd = vd * vd;
    #pragma unroll
    for (int off = 32; off; off >>= 1) sd += __shfl_xor(sd, off);
    if (d == 0) inv_n64[k] = 1.0 / fmax(sqrt(sd), 1e-12);

    if (k == 0) {
        for (int i = d; i < KCODES; i += 64) count[i] = 0;
        if (d == 0) accum[0] = 0.0;
    }
}

// ---------------- main: fused distance GEMM + argmax (+fp64 recheck for near-ties)
__global__ __launch_bounds__(256) void vq_main(
    const float* __restrict__ inputs, const float* __restrict__ w,
    const float* __restrict__ cbT, const double* __restrict__ inv_n64,
    int* __restrict__ g_idx, int* __restrict__ count)
{
    __shared__ float lds_z[DIM * LROW];    // z^T [d][token], normalized
    __shared__ float lds_cb[DIM * LROW];   // cb^T chunk [d][code]
    __shared__ int   s_idx[TPB];
    __shared__ int   s_nflag;
    __shared__ int   s_flags[TPB];
    __shared__ double s_z64[DIM];
    __shared__ double s_rv[256];
    __shared__ int    s_ri[256];

    const int tid = threadIdx.x;
    const int n0  = blockIdx.x * TPB;
    const int tx  = tid & 15;   // token group: tokens [tx*8, tx*8+8)
    const int ty  = tid >> 4;   // code group within chunk: codes [ty*8, ty*8+8)

    // stage z transposed into LDS (coalesced global float4 loads)
    #pragma unroll
    for (int i = 0; i < 8; i++) {
        int f   = i * 256 + tid;        // float4 index, 16 per token
        int tok = f >> 4;
        int d4  = (f & 15) * 4;
        float4 v = *(const float4*)&inputs[(size_t)(n0 + tok) * DIM + d4];
        lds_z[(d4 + 0) * LROW + tok] = v.x;
        lds_z[(d4 + 1) * LROW + tok] = v.y;
        lds_z[(d4 + 2) * LROW + tok] = v.z;
        lds_z[(d4 + 3) * LROW + tok] = v.w;
    }
    if (tid == 0) s_nflag = 0;
    __syncthreads();

    // normalize each token column in-place (fp32, like F.normalize)
    if (tid < TPB) {
        float s = 0.f;
        for (int d = 0; d < DIM; d++) { float v = lds_z[d * LROW + tid]; s += v * v; }
        float scale = 1.0f / fmaxf(sqrtf(s), 1e-12f);
        for (int d = 0; d < DIM; d++) lds_z[d * LROW + tid] *= scale;
    }

    float best[8], second[8]; int bidx[8];
    #pragma unroll
    for (int i = 0; i < 8; i++) { best[i] = -1e30f; second[i] = -1e30f; bidx[i] = 0; }

    for (int c = 0; c < KCODES / KC; c++) {
        __syncthreads();
        // stage cb chunk (coalesced)
        #pragma unroll
        for (int i = 0; i < 8; i++) {
            int f  = i * 256 + tid;       // float4 index within 64 x 32
            int r  = f >> 5;              // d row
            int c4 = (f & 31) * 4;        // col (float)
            float4 v = *(const float4*)&cbT[(size_t)r * KCODES + c * KC + c4];
            *(float4*)&lds_cb[r * LROW + c4] = v;
        }
        __syncthreads();

        float acc[8][8];
        #pragma unroll
        for (int i = 0; i < 8; i++)
            #pragma unroll
            for (int j = 0; j < 8; j++) acc[i][j] = 0.f;

        #pragma unroll 2
        for (int d = 0; d < DIM; d++) {
            float4 a0 = *(float4*)&lds_z[d * LROW + tx * 8];
            float4 a1 = *(float4*)&lds_z[d * LROW + tx * 8 + 4];
            float4 b0 = *(float4*)&lds_cb[d * LROW + ty * 8];
            float4 b1 = *(float4*)&lds_cb[d * LROW + ty * 8 + 4];
            float a[8] = {a0.x, a0.y, a0.z, a0.w, a1.x, a1.y, a1.z, a1.w};
            float b[8] = {b0.x, b0.y, b0.z, b0.w, b1.x, b1.y, b1.z, b1.w};
            #pragma unroll
            for (int i = 0; i < 8; i++)
                #pragma unroll
                for (int j = 0; j < 8; j++)
                    acc[i][j] = fmaf(a[i], b[j], acc[i][j]);
        }

        #pragma unroll
        for (int i = 0; i < 8; i++)
            #pragma unroll
            for (int j = 0; j < 8; j++) {
                float v = acc[i][j];
                int   k = c * KC + ty * 8 + j;   // ascending k within thread
                if (v > best[i]) { second[i] = best[i]; best[i] = v; bidx[i] = k; }
                else if (v > second[i]) second[i] = v;
            }
    }

    // cross-thread (over ty) argmax reduction; alias lds_cb as scratch
    __syncthreads();
    float* rbest = lds_cb;
    float* rsec  = lds_cb + TPB * 16;
    int*   ridx  = (int*)(lds_cb + 2 * TPB * 16);
    #pragma unroll
    for (int i = 0; i < 8; i++) {
        int t = tx * 8 + i;
        rbest[t * 16 + ty] = best[i];
        rsec [t * 16 + ty] = second[i];
        ridx [t * 16 + ty] = bidx[i];
    }
    __syncthreads();
    if (tid < TPB) {
        float B = -1e30f, S = -1e30f; int I = 0x7fffffff;
        for (int e = 0; e < 16; e++) {
            float b  = rbest[tid * 16 + e];
            float s2 = rsec [tid * 16 + e];
            int   ib = ridx [tid * 16 + e];
            if (b > B || (b == B && ib < I)) { S = fmaxf(fmaxf(S, B), s2); B = b; I = ib; }
            else S = fmaxf(S, b);
        }
        s_idx[tid] = I;
        if (B - S < TIE_EPS) { int p = atomicAdd(&s_nflag, 1); s_flags[p] = tid; }
    }
    __syncthreads();

    // fp64 full rescan for near-tie tokens (block-cooperative, rare)
    int nf = s_nflag;
    for (int f = 0; f < nf; f++) {
        int t = s_flags[f];
        size_t n = (size_t)n0 + t;
        if (tid < 64) {
            double zd = (double)inputs[n * DIM + tid];
            double sd = zd * zd;
            #pragma unroll
            for (int off = 32; off; off >>= 1) sd += __shfl_xor(sd, off);
            double inv = 1.0 / fmax(sqrt(sd), 1e-12);
            s_z64[tid] = zd * inv;
        }
        __syncthreads();
        double bv = -1e300; int bi = 0x7fffffff;
        #pragma unroll
        for (int cc = 0; cc < 4; cc++) {
            int k = tid * 4 + cc;                 // ascending k per thread
            double invk = inv_n64[k];
            double dot = 0.0;
            for (int d = 0; d < DIM; d++)
                dot += s_z64[d] * ((double)w[k * DIM + d] * invk);
            if (dot > bv) { bv = dot; bi = k; }
        }
        s_rv[tid] = bv; s_ri[tid] = bi;
        __syncthreads();
        for (int st = 128; st; st >>= 1) {
            if (tid < st) {
                double ov = s_rv[tid + st]; int oi = s_ri[tid + st];
                if (ov > s_rv[tid] || (ov == s_rv[tid] && oi < s_ri[tid])) {
                    s_rv[tid] = ov; s_ri[tid] = oi;
                }
            }
            __syncthreads();
        }
        if (tid == 0) s_idx[t] = s_ri[0];
        __syncthreads();
    }

    if (tid < TPB) {
        int I = s_idx[tid];
        g_idx[n0 + tid] = I;
        atomicAdd(&count[I], 1);
    }
}

// ---------------- gather: quantized copy, loss partials, one-hot scatter
__global__ __launch_bounds__(256) void vq_gather(
    const float* __restrict__ inputs, const float* __restrict__ w,
    const int* __restrict__ g_idx, float* __restrict__ out_q,
    float* __restrict__ out_enc, double* __restrict__ accum)
{
    __shared__ float s_part[4];
    int g  = blockIdx.x * 256 + threadIdx.x;   // float4 id over [N][16]
    int n  = g >> 4;
    int d4 = (g & 15) * 4;
    int k  = g_idx[n];
    float4 q = *(const float4*)&w[(size_t)k * DIM + d4];
    float4 z = *(const float4*)&inputs[(size_t)n * DIM + d4];
    // out_q base is d_out+1 (not 16B aligned) -> scalar stores
    size_t ob = (size_t)n * DIM + d4;
    out_q[ob + 0] = q.x; out_q[ob + 1] = q.y; out_q[ob + 2] = q.z; out_q[ob + 3] = q.w;
    if ((g & 15) == 0) out_enc[(size_t)n * KCODES + k] = 1.0f;

    float dx = q.x - z.x, dy = q.y - z.y, dz = q.z - z.z, dw = q.w - z.w;
    float s = dx * dx + dy * dy + dz * dz + dw * dw;
    #pragma unroll
    for (int off = 32; off; off >>= 1) s += __shfl_xor(s, off);
    int lane = threadIdx.x & 63, wv = threadIdx.x >> 6;
    if (lane == 0) s_part[wv] = s;
    __syncthreads();
    if (threadIdx.x == 0) {
        float tot = s_part[0] + s_part[1] + s_part[2] + s_part[3];
        atomicAdd(accum, (double)tot);
    }
}

// ---------------- finalize: loss scalar + perplexity
__global__ __launch_bounds__(256) void vq_final(
    const int* __restrict__ count, const double* __restrict__ accum,
    float* __restrict__ out_loss, float* __restrict__ out_perp)
{
    __shared__ double s_red[256];
    int tid = threadIdx.x;
    double local = 0.0;
    for (int k = tid; k < KCODES; k += 256) {
        double p = (double)count[k] / (double)N_TOK;
        local += p * log(p + 1e-10);
    }
    s_red[tid] = local;
    __syncthreads();
    for (int st = 128; st; st >>= 1) {
        if (tid < st) s_red[tid] += s_red[tid + st];
        __syncthreads();
    }
    if (tid == 0) {
        out_perp[0] = (float)exp(-s_red[0]);
        out_loss[0] = (float)(1.25 * accum[0] / ((double)N_TOK * (double)DIM));
    }
}

extern "C" void kernel_launch(void* const* d_in, const int* in_sizes, int n_in,
                              void* d_out, int out_size, void* d_ws, size_t ws_size,
                              hipStream_t stream) {
    const float* inputs = (const float*)d_in[0];
    const float* weight = (const float*)d_in[1];
    float* out      = (float*)d_out;
    float* out_loss = out;                               // [1]
    float* out_q    = out + 1;                           // [N*D]
    float* out_perp = out + 1 + (size_t)N_TOK * DIM;     // [1]
    float* out_enc  = out_perp + 1;                      // [N*K]

    char* ws = (char*)d_ws;
    float*  cbT     = (float*)ws;                                    // 262144 B
    double* inv_n64 = (double*)(ws + 262144);                        // 8192 B
    int*    g_idx   = (int*)(ws + 262144 + 8192);                    // 524288 B
    int*    count   = (int*)(ws + 262144 + 8192 + 524288);           // 4096 B
    double* accum   = (double*)(ws + 262144 + 8192 + 524288 + 4096); // 8 B

    hipMemsetAsync(out_enc, 0, (size_t)N_TOK * KCODES * sizeof(float), stream);
    vq_prep<<<KCODES, 64, 0, stream>>>(weight, cbT, inv_n64, count, accum);
    vq_main<<<N_TOK / TPB, 256, 0, stream>>>(inputs, weight, cbT, inv_n64, g_idx, count);
    vq_gather<<<(N_TOK * 16) / 256, 256, 0, stream>>>(inputs, weight, g_idx, out_q, out_enc, accum);
    vq_final<<<1, 256, 0, stream>>>(count, accum, out_loss, out_perp);
}

// Round 2
// 958.943 us; speedup vs baseline: 1.2296x; 1.2296x over previous
//
#include <hip/hip_runtime.h>
#include <math.h>

#define N_TOK 131072
#define DIM 64
#define KCODES 1024
#define TPB 64          // tokens per block (main kernel, 4 waves x 16)
#define TIE_EPS 1e-4f

typedef __attribute__((ext_vector_type(8))) short short8;
typedef __attribute__((ext_vector_type(4))) float float4v;

static __device__ inline unsigned short f2bf(float x) {
    unsigned u = __float_as_uint(x);
    unsigned r = (u + 0x7FFF + ((u >> 16) & 1)) >> 16;
    return (unsigned short)r;
}
static __device__ inline float bf2f(unsigned short b) {
    return __uint_as_float(((unsigned)b) << 16);
}

// ---------------- prep: normalize codebook -> bf16 hi/lo B-fragments, fp64 inv norms, zero counters
__global__ __launch_bounds__(64) void vq_prep(
    const float* __restrict__ w, unsigned short* __restrict__ bfrag_hi,
    unsigned short* __restrict__ bfrag_lo, double* __restrict__ inv_n64,
    int* __restrict__ count)
{
    int k = blockIdx.x;   // code
    int d = threadIdx.x;  // dim
    float v = w[k * DIM + d];
    float s = v * v;
    #pragma unroll
    for (int off = 32; off; off >>= 1) s += __shfl_xor(s, off);
    float den = fmaxf(sqrtf(s), 1e-12f);
    float nv = v / den;
    unsigned short hi = f2bf(nv);
    unsigned short lo = f2bf(nv - bf2f(hi));

    // B-fragment position for mfma_f32_16x16x32_bf16: lane l holds B[n=l&15][kk=(l>>4)*8+j]
    int t  = k >> 4;          // code tile
    int nl = k & 15;          // n within tile
    int s2 = d >> 5;          // k-step (0,1)
    int q  = (d >> 3) & 3;    // quad
    int j  = d & 7;
    int l  = nl + 16 * q;
    size_t pos = ((size_t)(t * 2 + s2) * 64 + l) * 8 + j;
    bfrag_hi[pos] = hi;
    bfrag_lo[pos] = lo;

    double vd = (double)v;
    double sd = vd * vd;
    #pragma unroll
    for (int off = 32; off; off >>= 1) sd += __shfl_xor(sd, off);
    if (d == 0) inv_n64[k] = 1.0 / fmax(sqrt(sd), 1e-12);

    if (k == 0) {
        for (int i = d; i < KCODES; i += 64) count[i] = 0;
    }
}

// merge (ob,os,oi) into (b,s,i) with lowest-index tie-break; equal best => gap 0 (flags rescan)
static __device__ inline void merge3(float& b, float& s, int& i, float ob, float os, int oi) {
    if (ob > b) { s = fmaxf(b, os); b = ob; i = oi; }
    else if (ob == b) { s = b; if (oi < i) i = oi; }
    else { s = fmaxf(s, ob); }
}

// ---------------- main: MFMA bf16-split distance + fused argmax (+fp64 recheck for near-ties)
__global__ __launch_bounds__(256) void vq_main(
    const float* __restrict__ inputs, const float* __restrict__ w,
    const unsigned short* __restrict__ bfrag_hi, const unsigned short* __restrict__ bfrag_lo,
    const double* __restrict__ inv_n64, int* __restrict__ g_idx, int* __restrict__ count)
{
    __shared__ float lds_z[TPB * 68];   // 64 tokens x 64 dims, stride 68
    __shared__ float s_inv[TPB];
    __shared__ int   s_idx[TPB];
    __shared__ int   s_nflag;
    __shared__ int   s_flags[TPB];
    __shared__ double s_z64[DIM];
    __shared__ double s_rv[256];
    __shared__ int    s_ri[256];

    const int tid  = threadIdx.x;
    const int n0   = blockIdx.x * TPB;
    const int lane = tid & 63;
    const int wv   = tid >> 6;
    const int col  = lane & 15;
    const int quad = lane >> 4;

    // stage 64 tokens (coalesced float4 global loads)
    #pragma unroll
    for (int i = 0; i < 4; i++) {
        int f   = i * 256 + tid;        // float4 index: 16 per token
        int tok = f >> 4;
        int d4  = (f & 15) * 4;
        float4 v = *(const float4*)&inputs[(size_t)(n0 + tok) * DIM + d4];
        *(float4*)&lds_z[tok * 68 + d4] = v;
    }
    if (tid == 0) s_nflag = 0;
    __syncthreads();

    // per-token inverse norms (fp32, matches F.normalize)
    if (tid < TPB) {
        float s = 0.f;
        for (int d = 0; d < DIM; d++) { float v = lds_z[tid * 68 + d]; s += v * v; }
        s_inv[tid] = 1.0f / fmaxf(sqrtf(s), 1e-12f);
    }
    __syncthreads();

    // build A fragments (hi/lo split): lane holds A[m=col][k=quad*8+j (+32*s)]
    short8 a_hi[2], a_lo[2];
    {
        float sc = s_inv[wv * 16 + col];
        #pragma unroll
        for (int s = 0; s < 2; s++) {
            int base = (wv * 16 + col) * 68 + quad * 8 + s * 32;
            #pragma unroll
            for (int j = 0; j < 8; j++) {
                float v = lds_z[base + j] * sc;
                unsigned short h = f2bf(v);
                unsigned short l = f2bf(v - bf2f(h));
                a_hi[s][j] = (short)h;
                a_lo[s][j] = (short)l;
            }
        }
    }

    float best[4], sec[4]; int bidx[4];
    #pragma unroll
    for (int i = 0; i < 4; i++) { best[i] = -1e30f; sec[i] = -1e30f; bidx[i] = 0x7fffffff; }

    const short8* bh_base = (const short8*)bfrag_hi;
    const short8* bl_base = (const short8*)bfrag_lo;

    for (int t = 0; t < KCODES / 16; t++) {
        const short8* bh = bh_base + (size_t)(t * 2) * 64 + lane;
        const short8* bl = bl_base + (size_t)(t * 2) * 64 + lane;
        short8 b0h = bh[0], b1h = bh[64];
        short8 b0l = bl[0], b1l = bl[64];

        float4v acc = {0.f, 0.f, 0.f, 0.f};
        acc = __builtin_amdgcn_mfma_f32_16x16x32_bf16(a_hi[0], b0h, acc, 0, 0, 0);
        acc = __builtin_amdgcn_mfma_f32_16x16x32_bf16(a_hi[0], b0l, acc, 0, 0, 0);
        acc = __builtin_amdgcn_mfma_f32_16x16x32_bf16(a_lo[0], b0h, acc, 0, 0, 0);
        acc = __builtin_amdgcn_mfma_f32_16x16x32_bf16(a_hi[1], b1h, acc, 0, 0, 0);
        acc = __builtin_amdgcn_mfma_f32_16x16x32_bf16(a_hi[1], b1l, acc, 0, 0, 0);
        acc = __builtin_amdgcn_mfma_f32_16x16x32_bf16(a_lo[1], b1h, acc, 0, 0, 0);

        int k = t * 16 + col;   // C/D: col=lane&15 -> code; rows quad*4+reg -> tokens
        #pragma unroll
        for (int i = 0; i < 4; i++) {
            float v = acc[i];
            if (v > best[i]) { sec[i] = best[i]; best[i] = v; bidx[i] = k; }
            else if (v > sec[i]) sec[i] = v;
        }
    }

    // butterfly argmax reduce across the 16 lanes of each quad group
    #pragma unroll
    for (int off = 1; off < 16; off <<= 1) {
        #pragma unroll
        for (int i = 0; i < 4; i++) {
            float ob = __shfl_xor(best[i], off);
            float os = __shfl_xor(sec[i], off);
            int   oi = __shfl_xor(bidx[i], off);
            merge3(best[i], sec[i], bidx[i], ob, os, oi);
        }
    }

    if (col == 0) {
        #pragma unroll
        for (int i = 0; i < 4; i++) {
            int m = wv * 16 + quad * 4 + i;   // token within block
            s_idx[m] = bidx[i];
            if (best[i] - sec[i] < TIE_EPS) {
                int p = atomicAdd(&s_nflag, 1);
                s_flags[p] = m;
            }
        }
    }
    __syncthreads();

    // fp64 full rescan for near-tie tokens (rare)
    int nf = s_nflag;
    for (int f = 0; f < nf; f++) {
        int t = s_flags[f];
        size_t n = (size_t)n0 + t;
        if (tid < 64) {
            double zd = (double)inputs[n * DIM + tid];
            double sd = zd * zd;
            #pragma unroll
            for (int off = 32; off; off >>= 1) sd += __shfl_xor(sd, off);
            double inv = 1.0 / fmax(sqrt(sd), 1e-12);
            s_z64[tid] = zd * inv;
        }
        __syncthreads();
        double bv = -1e300; int bi = 0x7fffffff;
        #pragma unroll
        for (int cc = 0; cc < 4; cc++) {
            int k = tid * 4 + cc;
            double invk = inv_n64[k];
            double dot = 0.0;
            for (int d = 0; d < DIM; d++)
                dot += s_z64[d] * ((double)w[k * DIM + d] * invk);
            if (dot > bv) { bv = dot; bi = k; }
        }
        s_rv[tid] = bv; s_ri[tid] = bi;
        __syncthreads();
        for (int st = 128; st; st >>= 1) {
            if (tid < st) {
                double ov = s_rv[tid + st]; int oi = s_ri[tid + st];
                if (ov > s_rv[tid] || (ov == s_rv[tid] && oi < s_ri[tid])) {
                    s_rv[tid] = ov; s_ri[tid] = oi;
                }
            }
            __syncthreads();
        }
        if (tid == 0) s_idx[t] = s_ri[0];
        __syncthreads();
    }

    if (tid < TPB) {
        int I = s_idx[tid];
        g_idx[n0 + tid] = I;
        atomicAdd(&count[I], 1);
    }
}

// ---------------- one-hot: fused zero-fill + scatter, coalesced float2 stores (base is 8B-aligned)
__global__ __launch_bounds__(256) void vq_onehot(
    const int* __restrict__ g_idx, float* __restrict__ out_enc)
{
    int tid = threadIdx.x;
    int n   = blockIdx.x * 2 + (tid >> 7);
    int k   = g_idx[n];
    int c2  = (tid & 127) * 2;
    float* row = out_enc + (size_t)n * KCODES;
    #pragma unroll
    for (int j = 0; j < 4; j++) {
        int p = c2 + j * 256;
        float2 v;
        v.x = (p     == k) ? 1.0f : 0.0f;
        v.y = (p + 1 == k) ? 1.0f : 0.0f;
        *(float2*)&row[p] = v;
    }
}

// ---------------- gather: quantized copy + per-block loss partials (no global contention)
__global__ __launch_bounds__(256) void vq_gather(
    const float* __restrict__ inputs, const float* __restrict__ w,
    const int* __restrict__ g_idx, float* __restrict__ out_q,
    double* __restrict__ partial)
{
    __shared__ float s_part[4];
    int g  = blockIdx.x * 256 + threadIdx.x;   // float4 id over [N][16]
    int n  = g >> 4;
    int d4 = (g & 15) * 4;
    int k  = g_idx[n];
    float4 q = *(const float4*)&w[(size_t)k * DIM + d4];
    float4 z = *(const float4*)&inputs[(size_t)n * DIM + d4];
    size_t ob = (size_t)n * DIM + d4;          // out_q base is d_out+1 (4B-aligned) -> scalar stores
    out_q[ob + 0] = q.x; out_q[ob + 1] = q.y; out_q[ob + 2] = q.z; out_q[ob + 3] = q.w;

    float dx = q.x - z.x, dy = q.y - z.y, dz = q.z - z.z, dw = q.w - z.w;
    float s = dx * dx + dy * dy + dz * dz + dw * dw;
    #pragma unroll
    for (int off = 32; off; off >>= 1) s += __shfl_xor(s, off);
    int lane = threadIdx.x & 63, wvv = threadIdx.x >> 6;
    if (lane == 0) s_part[wvv] = s;
    __syncthreads();
    if (threadIdx.x == 0)
        partial[blockIdx.x] = (double)(s_part[0] + s_part[1] + s_part[2] + s_part[3]);
}

// ---------------- finalize: loss scalar + perplexity
__global__ __launch_bounds__(256) void vq_final(
    const int* __restrict__ count, const double* __restrict__ partial,
    float* __restrict__ out_loss, float* __restrict__ out_perp)
{
    __shared__ double s_red[256];
    __shared__ double s_red2[256];
    int tid = threadIdx.x;
    double local = 0.0, lsum = 0.0;
    for (int k = tid; k < KCODES; k += 256) {
        double p = (double)count[k] / (double)N_TOK;
        local += p * log(p + 1e-10);
    }
    for (int i = tid; i < 8192; i += 256) lsum += partial[i];
    s_red[tid] = local;
    s_red2[tid] = lsum;
    __syncthreads();
    for (int st = 128; st; st >>= 1) {
        if (tid < st) { s_red[tid] += s_red[tid + st]; s_red2[tid] += s_red2[tid + st]; }
        __syncthreads();
    }
    if (tid == 0) {
        out_perp[0] = (float)exp(-s_red[0]);
        out_loss[0] = (float)(1.25 * s_red2[0] / ((double)N_TOK * (double)DIM));
    }
}

extern "C" void kernel_launch(void* const* d_in, const int* in_sizes, int n_in,
                              void* d_out, int out_size, void* d_ws, size_t ws_size,
                              hipStream_t stream) {
    const float* inputs = (const float*)d_in[0];
    const float* weight = (const float*)d_in[1];
    float* out      = (float*)d_out;
    float* out_loss = out;                               // [1]
    float* out_q    = out + 1;                           // [N*D]
    float* out_perp = out + 1 + (size_t)N_TOK * DIM;     // [1]
    float* out_enc  = out_perp + 1;                      // [N*K]

    char* ws = (char*)d_ws;
    unsigned short* bfrag_hi = (unsigned short*)ws;                  // 131072 B
    unsigned short* bfrag_lo = (unsigned short*)(ws + 131072);       // 131072 B
    double* inv_n64 = (double*)(ws + 262144);                        // 8192 B
    int*    g_idx   = (int*)(ws + 270336);                           // 524288 B
    int*    count   = (int*)(ws + 794624);                           // 4096 B
    double* partial = (double*)(ws + 798720);                        // 65536 B

    vq_prep<<<KCODES, 64, 0, stream>>>(weight, bfrag_hi, bfrag_lo, inv_n64, count);
    vq_main<<<N_TOK / TPB, 256, 0, stream>>>(inputs, weight, bfrag_hi, bfrag_lo,
                                             inv_n64, g_idx, count);
    vq_onehot<<<N_TOK / 2, 256, 0, stream>>>(g_idx, out_enc);
    vq_gather<<<(N_TOK * 16) / 256, 256, 0, stream>>>(inputs, weight, g_idx, out_q, partial);
    vq_final<<<1, 256, 0, stream>>>(count, partial, out_loss, out_perp);
}

// Round 3
// 692.860 us; speedup vs baseline: 1.7018x; 1.3840x over previous
//
#include <hip/hip_runtime.h>
#include <math.h>

#define N_TOK 131072
#define DIM 64
#define KCODES 1024
#define TPB 128         // tokens per block (main kernel): 4 waves x 2 sets x 16
#define TIE_EPS 1e-4f

typedef __attribute__((ext_vector_type(8))) short short8;
typedef __attribute__((ext_vector_type(4))) float float4v;

static __device__ inline unsigned short f2bf(float x) {
    unsigned u = __float_as_uint(x);
    unsigned r = (u + 0x7FFF + ((u >> 16) & 1)) >> 16;
    return (unsigned short)r;
}
static __device__ inline float bf2f(unsigned short b) {
    return __uint_as_float(((unsigned)b) << 16);
}

// ---------------- prep: normalized codebook -> bf16 hi/lo B-fragments, norms, zero counters
__global__ __launch_bounds__(64) void vq_prep(
    const float* __restrict__ w, unsigned short* __restrict__ bfrag_hi,
    unsigned short* __restrict__ bfrag_lo, double* __restrict__ inv_n64,
    float* __restrict__ nw, int* __restrict__ count, int* __restrict__ nflag,
    double* __restrict__ delta)
{
    int k = blockIdx.x;   // code
    int d = threadIdx.x;  // dim
    float v = w[k * DIM + d];
    float s = v * v;
    #pragma unroll
    for (int off = 32; off; off >>= 1) s += __shfl_xor(s, off);
    float den = fmaxf(sqrtf(s), 1e-12f);
    float nv = v / den;
    unsigned short hi = f2bf(nv);
    unsigned short lo = f2bf(nv - bf2f(hi));

    // B-fragment for mfma_f32_16x16x32_bf16: lane l holds B[n=l&15][kk=(l>>4)*8+j]
    int t  = k >> 4;          // code tile
    int nl = k & 15;
    int s2 = d >> 5;          // k-step
    int q  = (d >> 3) & 3;
    int j  = d & 7;
    int l  = nl + 16 * q;
    size_t pos = ((size_t)(t * 2 + s2) * 64 + l) * 8 + j;
    bfrag_hi[pos] = hi;
    bfrag_lo[pos] = lo;

    double vd = (double)v;
    double sd = vd * vd;
    #pragma unroll
    for (int off = 32; off; off >>= 1) sd += __shfl_xor(sd, off);
    if (d == 0) {
        inv_n64[k] = 1.0 / fmax(sqrt(sd), 1e-12);
        nw[k] = den;
    }
    if (k == 0) {
        for (int i = d; i < KCODES; i += 64) count[i] = 0;
        if (d == 0) { nflag[0] = 0; delta[0] = 0.0; }
    }
}

static __device__ inline void merge3(float& b, float& s, int& i, float ob, float os, int oi) {
    if (ob > b) { s = fmaxf(b, os); b = ob; i = oi; }
    else if (ob == b) { s = b; if (oi < i) i = oi; }
    else { s = fmaxf(s, ob); }
}

// ---------------- main: MFMA distance + argmax + FUSED epilogue (one-hot, quantized, loss)
__global__ __launch_bounds__(256, 3) void vq_main(
    const float* __restrict__ inputs, const float* __restrict__ w,
    const unsigned short* __restrict__ bfrag_hi, const unsigned short* __restrict__ bfrag_lo,
    const float* __restrict__ nw, int* __restrict__ g_idx, int* __restrict__ count,
    double* __restrict__ partial, int* __restrict__ nflag, int* __restrict__ flags,
    float* __restrict__ out_q, float* __restrict__ out_enc)
{
    __shared__ int   s_idx[TPB];
    __shared__ float s_part[4];

    const int tid  = threadIdx.x;
    const int lane = tid & 63;
    const int wv   = tid >> 6;
    const int col  = lane & 15;
    const int quad = lane >> 4;
    const int n0   = blockIdx.x * TPB;

    // ---- A fragments straight from global (no LDS). 2 sets x 16 tokens per wave.
    short8 ah[2][2], al[2][2];
    float n2z[2];
    #pragma unroll
    for (int s = 0; s < 2; s++) {
        int m = n0 + wv * 32 + s * 16 + col;
        const float* zp = inputs + (size_t)m * DIM + quad * 8;
        float4 f0 = *(const float4*)zp;
        float4 f1 = *(const float4*)(zp + 4);
        float4 f2 = *(const float4*)(zp + 32);
        float4 f3 = *(const float4*)(zp + 36);
        float v[16] = {f0.x,f0.y,f0.z,f0.w, f1.x,f1.y,f1.z,f1.w,
                       f2.x,f2.y,f2.z,f2.w, f3.x,f3.y,f3.z,f3.w};
        float ss = 0.f;
        #pragma unroll
        for (int j = 0; j < 16; j++) ss += v[j] * v[j];
        ss += __shfl_xor(ss, 16);   // quad-reduction: lanes differing in bits 4..5
        ss += __shfl_xor(ss, 32);
        n2z[s] = ss;
        float inv = 1.0f / fmaxf(sqrtf(ss), 1e-12f);   // any per-token scale is argmax-safe
        #pragma unroll
        for (int j = 0; j < 8; j++) {
            float x0 = v[j] * inv;
            unsigned short h0 = f2bf(x0);
            ah[s][0][j] = (short)h0;
            al[s][0][j] = (short)f2bf(x0 - bf2f(h0));
            float x1 = v[8 + j] * inv;
            unsigned short h1 = f2bf(x1);
            ah[s][1][j] = (short)h1;
            al[s][1][j] = (short)f2bf(x1 - bf2f(h1));
        }
    }

    // ---- K loop over 64 code tiles with B prefetch
    float best[8], sec[8]; int bidx[8];
    #pragma unroll
    for (int i = 0; i < 8; i++) { best[i] = -1e30f; sec[i] = -1e30f; bidx[i] = 0x7fffffff; }

    const short8* bhp = (const short8*)bfrag_hi;
    const short8* blp = (const short8*)bfrag_lo;
    short8 c0h = bhp[lane], c1h = bhp[64 + lane];
    short8 c0l = blp[lane], c1l = blp[64 + lane];

    for (int t = 0; t < 64; t++) {
        int tn = (t < 63) ? (t + 1) : 63;       // branch-free prefetch (tile 63 re-read, unused)
        size_t o = (size_t)(2 * tn) * 64 + lane;
        short8 p0h = bhp[o], p1h = bhp[o + 64];
        short8 p0l = blp[o], p1l = blp[o + 64];

        float4v acc0 = {0.f,0.f,0.f,0.f}, acc1 = {0.f,0.f,0.f,0.f};
        acc0 = __builtin_amdgcn_mfma_f32_16x16x32_bf16(ah[0][0], c0h, acc0, 0,0,0);
        acc1 = __builtin_amdgcn_mfma_f32_16x16x32_bf16(ah[1][0], c0h, acc1, 0,0,0);
        acc0 = __builtin_amdgcn_mfma_f32_16x16x32_bf16(al[0][0], c0h, acc0, 0,0,0);
        acc1 = __builtin_amdgcn_mfma_f32_16x16x32_bf16(al[1][0], c0h, acc1, 0,0,0);
        acc0 = __builtin_amdgcn_mfma_f32_16x16x32_bf16(ah[0][0], c0l, acc0, 0,0,0);
        acc1 = __builtin_amdgcn_mfma_f32_16x16x32_bf16(ah[1][0], c0l, acc1, 0,0,0);
        acc0 = __builtin_amdgcn_mfma_f32_16x16x32_bf16(ah[0][1], c1h, acc0, 0,0,0);
        acc1 = __builtin_amdgcn_mfma_f32_16x16x32_bf16(ah[1][1], c1h, acc1, 0,0,0);
        acc0 = __builtin_amdgcn_mfma_f32_16x16x32_bf16(al[0][1], c1h, acc0, 0,0,0);
        acc1 = __builtin_amdgcn_mfma_f32_16x16x32_bf16(al[1][1], c1h, acc1, 0,0,0);
        acc0 = __builtin_amdgcn_mfma_f32_16x16x32_bf16(ah[0][1], c1l, acc0, 0,0,0);
        acc1 = __builtin_amdgcn_mfma_f32_16x16x32_bf16(ah[1][1], c1l, acc1, 0,0,0);

        int k = t * 16 + col;
        #pragma unroll
        for (int i = 0; i < 4; i++) {
            float v0 = acc0[i];
            bool g0 = v0 > best[i];
            sec[i]  = fmaxf(sec[i], fminf(v0, best[i]));
            best[i] = fmaxf(best[i], v0);
            bidx[i] = g0 ? k : bidx[i];
            float v1 = acc1[i];
            bool g1 = v1 > best[4 + i];
            sec[4 + i]  = fmaxf(sec[4 + i], fminf(v1, best[4 + i]));
            best[4 + i] = fmaxf(best[4 + i], v1);
            bidx[4 + i] = g1 ? k : bidx[4 + i];
        }
        c0h = p0h; c1h = p1h; c0l = p0l; c1l = p1l;
    }

    // ---- cross-lane argmax over the 16 code-columns
    #pragma unroll
    for (int off = 1; off < 16; off <<= 1) {
        #pragma unroll
        for (int i = 0; i < 8; i++) {
            float ob = __shfl_xor(best[i], off);
            float os = __shfl_xor(sec[i], off);
            int   oi = __shfl_xor(bidx[i], off);
            merge3(best[i], sec[i], bidx[i], ob, os, oi);
        }
    }

    // ---- per-token bookkeeping at col==0 lanes; loss via |z|^2 - 2 cos |z||w| + |w|^2
    float lsum = 0.f;
    #pragma unroll
    for (int s = 0; s < 2; s++) {
        #pragma unroll
        for (int i = 0; i < 4; i++) {
            int r = s * 4 + i;
            float n2 = __shfl(n2z[s], quad * 4 + i);   // all lanes participate
            if (col == 0) {
                int u  = quad * 4 + i;
                int tl = wv * 32 + s * 16 + u;
                int k  = bidx[r];
                s_idx[tl] = k;
                g_idx[n0 + tl] = k;
                atomicAdd(&count[k], 1);
                if (best[r] - sec[r] < TIE_EPS) {
                    int p = atomicAdd(nflag, 1);
                    flags[p] = n0 + tl;
                }
                float nwk = nw[k];
                float zw  = best[r] * sqrtf(n2) * nwk;
                lsum += n2 - 2.f * zw + nwk * nwk;
            }
        }
    }
    lsum += __shfl_xor(lsum, 16);
    lsum += __shfl_xor(lsum, 32);
    if (lane == 0) s_part[wv] = lsum;
    __syncthreads();
    if (tid == 0)
        partial[blockIdx.x] = (double)(s_part[0] + s_part[1] + s_part[2] + s_part[3]);

    // ---- fused epilogue: quantized rows (coalesced scalar) + one-hot rows (float2)
    const size_t qbase = (size_t)n0 * DIM;
    #pragma unroll 4
    for (int i2 = 0; i2 < 32; i2++) {
        int p = i2 * 256 + tid;
        int r = p >> 6, c = p & 63;
        int k = s_idx[r];
        out_q[qbase + p] = w[(size_t)k * DIM + c];
    }
    float* erow = out_enc + (size_t)(n0 + wv * 32) * KCODES + lane * 2;
    #pragma unroll 2
    for (int r = 0; r < 32; r++) {
        int k = s_idx[wv * 32 + r];
        #pragma unroll
        for (int j = 0; j < 8; j++) {
            int c2 = j * 128 + lane * 2;
            float2 v;
            v.x = (c2     == k) ? 1.f : 0.f;
            v.y = (c2 + 1 == k) ? 1.f : 0.f;
            *(float2*)(erow + j * 128 - lane * 2 + lane * 2) = v;   // erow + j*128
        }
        erow += KCODES;
    }
}

// ---------------- rescan: fp64 exact argmin for near-tie tokens; patch outputs
__global__ __launch_bounds__(64) void vq_rescan(
    const float* __restrict__ inputs, const float* __restrict__ w,
    const double* __restrict__ inv_n64, const int* __restrict__ g_idx,
    const int* __restrict__ flags, const int* __restrict__ nflag,
    int* __restrict__ count, float* __restrict__ out_q,
    float* __restrict__ out_enc, double* __restrict__ delta)
{
    __shared__ double sz[64];
    int lane = threadIdx.x;
    int nf = nflag[0];
    for (int i = blockIdx.x; i < nf; i += gridDim.x) {
        int tok = flags[i];
        double zd = (double)inputs[(size_t)tok * DIM + lane];
        double ss = zd * zd;
        #pragma unroll
        for (int off = 32; off; off >>= 1) ss += __shfl_xor(ss, off);
        sz[lane] = zd / fmax(sqrt(ss), 1e-12);
        __syncthreads();
        double bv = -1e300; int bi = 0x7fffffff;
        for (int c = 0; c < 16; c++) {
            int k = c * 64 + lane;
            double invk = inv_n64[k];
            double dot = 0.0;
            #pragma unroll 8
            for (int d = 0; d < DIM; d++)
                dot += sz[d] * ((double)w[(size_t)k * DIM + d] * invk);
            if (dot > bv) { bv = dot; bi = k; }
        }
        #pragma unroll
        for (int off = 1; off < 64; off <<= 1) {
            double ov = __shfl_xor(bv, off);
            int   oi = __shfl_xor(bi, off);
            if (ov > bv || (ov == bv && oi < bi)) { bv = ov; bi = oi; }
        }
        int kold = g_idx[tok];
        if (bi != kold) {
            double wn = (double)w[(size_t)bi * DIM + lane];
            double wo = (double)w[(size_t)kold * DIM + lane];
            double zr = (double)inputs[(size_t)tok * DIM + lane];
            double a = wn * wn - wo * wo - 2.0 * zr * (wn - wo);
            #pragma unroll
            for (int off = 32; off; off >>= 1) a += __shfl_xor(a, off);
            out_q[(size_t)tok * DIM + lane] = (float)wn;
            if (lane == 0) {
                atomicAdd(&count[kold], -1);
                atomicAdd(&count[bi], 1);
                out_enc[(size_t)tok * KCODES + kold] = 0.f;
                out_enc[(size_t)tok * KCODES + bi]   = 1.f;
                atomicAdd(delta, a);
            }
        }
        __syncthreads();
    }
}

// ---------------- finalize: loss scalar + perplexity
__global__ __launch_bounds__(256) void vq_final(
    const int* __restrict__ count, const double* __restrict__ partial,
    const double* __restrict__ delta, float* __restrict__ out_loss,
    float* __restrict__ out_perp)
{
    __shared__ double s1[256], s2[256];
    int tid = threadIdx.x;
    double lp = 0.0, ls = 0.0;
    for (int k = tid; k < KCODES; k += 256) {
        double p = (double)count[k] / (double)N_TOK;
        lp += p * log(p + 1e-10);
    }
    for (int i = tid; i < 1024; i += 256) ls += partial[i];
    s1[tid] = lp; s2[tid] = ls;
    __syncthreads();
    for (int st = 128; st; st >>= 1) {
        if (tid < st) { s1[tid] += s1[tid + st]; s2[tid] += s2[tid + st]; }
        __syncthreads();
    }
    if (tid == 0) {
        out_perp[0] = (float)exp(-s1[0]);
        out_loss[0] = (float)(1.25 * (s2[0] + delta[0]) / ((double)N_TOK * (double)DIM));
    }
}

extern "C" void kernel_launch(void* const* d_in, const int* in_sizes, int n_in,
                              void* d_out, int out_size, void* d_ws, size_t ws_size,
                              hipStream_t stream) {
    const float* inputs = (const float*)d_in[0];
    const float* weight = (const float*)d_in[1];
    float* out      = (float*)d_out;
    float* out_loss = out;                               // [1]
    float* out_q    = out + 1;                           // [N*D]
    float* out_perp = out + 1 + (size_t)N_TOK * DIM;     // [1]
    float* out_enc  = out_perp + 1;                      // [N*K], 8B-aligned

    char* ws = (char*)d_ws;
    unsigned short* bfrag_hi = (unsigned short*)ws;                  // 131072 B
    unsigned short* bfrag_lo = (unsigned short*)(ws + 131072);       // 131072 B
    double* inv_n64 = (double*)(ws + 262144);                        // 8192 B
    float*  nw      = (float*)(ws + 270336);                         // 4096 B
    int*    g_idx   = (int*)(ws + 274432);                           // 524288 B
    int*    count   = (int*)(ws + 798720);                           // 4096 B
    double* partial = (double*)(ws + 802816);                        // 8192 B
    double* delta   = (double*)(ws + 811008);                        // 8 B
    int*    nflag   = (int*)(ws + 811016);                           // 4 B
    int*    flags   = (int*)(ws + 811020);                           // 524288 B

    vq_prep<<<KCODES, 64, 0, stream>>>(weight, bfrag_hi, bfrag_lo, inv_n64, nw,
                                       count, nflag, delta);
    vq_main<<<N_TOK / TPB, 256, 0, stream>>>(inputs, weight, bfrag_hi, bfrag_lo, nw,
                                             g_idx, count, partial, nflag, flags,
                                             out_q, out_enc);
    vq_rescan<<<256, 64, 0, stream>>>(inputs, weight, inv_n64, g_idx, flags, nflag,
                                      count, out_q, out_enc, delta);
    vq_final<<<1, 256, 0, stream>>>(count, partial, delta, out_loss, out_perp);
}

// Round 4
// 679.369 us; speedup vs baseline: 1.7356x; 1.0199x over previous
//
#include <hip/hip_runtime.h>
#include <math.h>

#define N_TOK 131072
#define DIM 64
#define KCODES 1024
#define TPB 128         // tokens per block (main kernel): 4 waves x 2 sets x 16
#define TIE_EPS 1e-4f

typedef __attribute__((ext_vector_type(8))) short short8;
typedef __attribute__((ext_vector_type(4))) float float4v;

static __device__ inline unsigned short f2bf(float x) {
    unsigned u = __float_as_uint(x);
    unsigned r = (u + 0x7FFF + ((u >> 16) & 1)) >> 16;
    return (unsigned short)r;
}
static __device__ inline float bf2f(unsigned short b) {
    return __uint_as_float(((unsigned)b) << 16);
}

// ---------------- prep: normalized codebook -> bf16 hi/lo B-fragments, norms, zero counters
__global__ __launch_bounds__(64) void vq_prep(
    const float* __restrict__ w, unsigned short* __restrict__ bfrag_hi,
    unsigned short* __restrict__ bfrag_lo, double* __restrict__ inv_n64,
    float* __restrict__ nw, int* __restrict__ count, int* __restrict__ nflag,
    double* __restrict__ delta)
{
    int k = blockIdx.x;   // code
    int d = threadIdx.x;  // dim
    float v = w[k * DIM + d];
    float s = v * v;
    #pragma unroll
    for (int off = 32; off; off >>= 1) s += __shfl_xor(s, off);
    float den = fmaxf(sqrtf(s), 1e-12f);
    float nv = v / den;
    unsigned short hi = f2bf(nv);
    unsigned short lo = f2bf(nv - bf2f(hi));

    // B-fragment for mfma_f32_16x16x32_bf16: lane l holds B[n=l&15][kk=(l>>4)*8+j]
    int t  = k >> 4;          // code tile
    int nl = k & 15;
    int s2 = d >> 5;          // k-step
    int q  = (d >> 3) & 3;
    int j  = d & 7;
    int l  = nl + 16 * q;
    size_t pos = ((size_t)(t * 2 + s2) * 64 + l) * 8 + j;
    bfrag_hi[pos] = hi;
    bfrag_lo[pos] = lo;

    double vd = (double)v;
    double sd = vd * vd;
    #pragma unroll
    for (int off = 32; off; off >>= 1) sd += __shfl_xor(sd, off);
    if (d == 0) {
        inv_n64[k] = 1.0 / fmax(sqrt(sd), 1e-12);
        nw[k] = den;
    }
    if (k == 0) {
        for (int i = d; i < KCODES; i += 64) count[i] = 0;
        if (d == 0) { nflag[0] = 0; delta[0] = 0.0; }
    }
}

static __device__ inline void merge3(float& b, float& s, int& i, float ob, float os, int oi) {
    if (ob > b) { s = fmaxf(b, os); b = ob; i = oi; }
    else if (ob == b) { s = b; if (oi < i) i = oi; }
    else { s = fmaxf(s, ob); }
}

// ---------------- main: MFMA distance + argmax + interleaved enc zero-fill + fused epilogue
__global__ __launch_bounds__(256, 4) void vq_main(
    const float* __restrict__ inputs, const float* __restrict__ w,
    const unsigned short* __restrict__ bfrag_hi, const unsigned short* __restrict__ bfrag_lo,
    const float* __restrict__ nw, int* __restrict__ g_idx, int* __restrict__ count,
    double* __restrict__ partial, int* __restrict__ nflag, int* __restrict__ flags,
    float* __restrict__ out_q, float* __restrict__ out_enc)
{
    __shared__ int   s_idx[TPB];
    __shared__ float s_part[4];

    const int tid  = threadIdx.x;
    const int lane = tid & 63;
    const int wv   = tid >> 6;
    const int col  = lane & 15;
    const int quad = lane >> 4;
    const int n0   = blockIdx.x * TPB;

    // ---- A fragments straight from global (no LDS). 2 sets x 16 tokens per wave.
    short8 ah[2][2], al[2][2];
    float n2z[2];
    #pragma unroll
    for (int s = 0; s < 2; s++) {
        int m = n0 + wv * 32 + s * 16 + col;
        const float* zp = inputs + (size_t)m * DIM + quad * 8;
        float4 f0 = *(const float4*)zp;
        float4 f1 = *(const float4*)(zp + 4);
        float4 f2 = *(const float4*)(zp + 32);
        float4 f3 = *(const float4*)(zp + 36);
        float v[16] = {f0.x,f0.y,f0.z,f0.w, f1.x,f1.y,f1.z,f1.w,
                       f2.x,f2.y,f2.z,f2.w, f3.x,f3.y,f3.z,f3.w};
        float ss = 0.f;
        #pragma unroll
        for (int j = 0; j < 16; j++) ss += v[j] * v[j];
        ss += __shfl_xor(ss, 16);   // quad-reduction: lanes differing in bits 4..5
        ss += __shfl_xor(ss, 32);
        n2z[s] = ss;
        float inv = 1.0f / fmaxf(sqrtf(ss), 1e-12f);   // any per-token scale is argmax-safe
        #pragma unroll
        for (int j = 0; j < 8; j++) {
            float x0 = v[j] * inv;
            unsigned short h0 = f2bf(x0);
            ah[s][0][j] = (short)h0;
            al[s][0][j] = (short)f2bf(x0 - bf2f(h0));
            float x1 = v[8 + j] * inv;
            unsigned short h1 = f2bf(x1);
            ah[s][1][j] = (short)h1;
            al[s][1][j] = (short)f2bf(x1 - bf2f(h1));
        }
    }

    // ---- interleaved zero-fill setup: block's enc span is [n0*1024, (n0+128)*1024)
    // out_enc is only 8B-aligned; float index rel 2 (mod 4) is 16B-aligned.
    float* enc0 = out_enc + (size_t)n0 * KCODES;
    float* zp4  = enc0 + 2 + tid * 4;                  // 16B-aligned float4 cursor
    const float4 zero4 = {0.f, 0.f, 0.f, 0.f};

    // ---- K loop over 64 code tiles with B prefetch + 2 zero stores/tile
    float best[8], sec[8]; int bidx[8];
    #pragma unroll
    for (int i = 0; i < 8; i++) { best[i] = -1e30f; sec[i] = -1e30f; bidx[i] = 0x7fffffff; }

    const short8* bhp = (const short8*)bfrag_hi;
    const short8* blp = (const short8*)bfrag_lo;
    short8 c0h = bhp[lane], c1h = bhp[64 + lane];
    short8 c0l = blp[lane], c1l = blp[64 + lane];

    for (int t = 0; t < 64; t++) {
        int tn = (t < 63) ? (t + 1) : 63;       // branch-free prefetch (tile 63 re-read, unused)
        size_t o = (size_t)(2 * tn) * 64 + lane;
        short8 p0h = bhp[o], p1h = bhp[o + 64];
        short8 p0l = blp[o], p1l = blp[o + 64];

        if (t < 63) {                           // i = 2t, 2t+1  (i = 126,127 done post-loop)
            *(float4*)zp4 = zero4;
            *(float4*)(zp4 + KCODES) = zero4;
            zp4 += 2 * KCODES;
        }

        float4v acc0 = {0.f,0.f,0.f,0.f}, acc1 = {0.f,0.f,0.f,0.f};
        acc0 = __builtin_amdgcn_mfma_f32_16x16x32_bf16(ah[0][0], c0h, acc0, 0,0,0);
        acc1 = __builtin_amdgcn_mfma_f32_16x16x32_bf16(ah[1][0], c0h, acc1, 0,0,0);
        acc0 = __builtin_amdgcn_mfma_f32_16x16x32_bf16(al[0][0], c0h, acc0, 0,0,0);
        acc1 = __builtin_amdgcn_mfma_f32_16x16x32_bf16(al[1][0], c0h, acc1, 0,0,0);
        acc0 = __builtin_amdgcn_mfma_f32_16x16x32_bf16(ah[0][0], c0l, acc0, 0,0,0);
        acc1 = __builtin_amdgcn_mfma_f32_16x16x32_bf16(ah[1][0], c0l, acc1, 0,0,0);
        acc0 = __builtin_amdgcn_mfma_f32_16x16x32_bf16(ah[0][1], c1h, acc0, 0,0,0);
        acc1 = __builtin_amdgcn_mfma_f32_16x16x32_bf16(ah[1][1], c1h, acc1, 0,0,0);
        acc0 = __builtin_amdgcn_mfma_f32_16x16x32_bf16(al[0][1], c1h, acc0, 0,0,0);
        acc1 = __builtin_amdgcn_mfma_f32_16x16x32_bf16(al[1][1], c1h, acc1, 0,0,0);
        acc0 = __builtin_amdgcn_mfma_f32_16x16x32_bf16(ah[0][1], c1l, acc0, 0,0,0);
        acc1 = __builtin_amdgcn_mfma_f32_16x16x32_bf16(ah[1][1], c1l, acc1, 0,0,0);

        int k = t * 16 + col;
        #pragma unroll
        for (int i = 0; i < 4; i++) {
            float v0 = acc0[i];
            sec[i]  = __builtin_amdgcn_fmed3f(best[i], sec[i], v0);
            bool g0 = v0 > best[i];
            best[i] = fmaxf(best[i], v0);
            bidx[i] = g0 ? k : bidx[i];
            float v1 = acc1[i];
            sec[4+i]  = __builtin_amdgcn_fmed3f(best[4+i], sec[4+i], v1);
            bool g1 = v1 > best[4 + i];
            best[4 + i] = fmaxf(best[4 + i], v1);
            bidx[4 + i] = g1 ? k : bidx[4 + i];
        }
        c0h = p0h; c1h = p1h; c0l = p0l; c1l = p1l;
    }

    // ---- zero-fill tail: i = 126,127 (skip q == 32767 overrun), plus the two float2 ends
    #pragma unroll
    for (int i = 126; i < 128; i++) {
        int q = i * 256 + tid;
        if (q < 32767) *(float4*)(enc0 + 2 + 4 * (size_t)q) = zero4;
    }
    if (tid == 0) {
        *(float2*)enc0 = make_float2(0.f, 0.f);
        *(float2*)(enc0 + (size_t)TPB * KCODES - 2) = make_float2(0.f, 0.f);
    }

    // ---- cross-lane argmax over the 16 code-columns
    #pragma unroll
    for (int off = 1; off < 16; off <<= 1) {
        #pragma unroll
        for (int i = 0; i < 8; i++) {
            float ob = __shfl_xor(best[i], off);
            float os = __shfl_xor(sec[i], off);
            int   oi = __shfl_xor(bidx[i], off);
            merge3(best[i], sec[i], bidx[i], ob, os, oi);
        }
    }

    // ---- per-token bookkeeping at col==0 lanes; loss via |z|^2 - 2 cos |z||w| + |w|^2
    float lsum = 0.f;
    #pragma unroll
    for (int s = 0; s < 2; s++) {
        #pragma unroll
        for (int i = 0; i < 4; i++) {
            int r = s * 4 + i;
            float n2 = __shfl(n2z[s], quad * 4 + i);   // all lanes participate
            if (col == 0) {
                int u  = quad * 4 + i;
                int tl = wv * 32 + s * 16 + u;
                int k  = bidx[r];
                s_idx[tl] = k;
                g_idx[n0 + tl] = k;
                atomicAdd(&count[k], 1);
                if (best[r] - sec[r] < TIE_EPS) {
                    int p = atomicAdd(nflag, 1);
                    flags[p] = n0 + tl;
                }
                float nwk = nw[k];
                float zw  = best[r] * sqrtf(n2) * nwk;
                lsum += n2 - 2.f * zw + nwk * nwk;
            }
        }
    }
    lsum += __shfl_xor(lsum, 16);
    lsum += __shfl_xor(lsum, 32);
    if (lane == 0) s_part[wv] = lsum;
    __syncthreads();   // also orders zero-fill stores before the 1.0f stores below
    if (tid == 0)
        partial[blockIdx.x] = (double)(s_part[0] + s_part[1] + s_part[2] + s_part[3]);

    // ---- epilogue: one-hot 1.0 stores + quantized rows (coalesced, L2-hot codebook gather)
    if (tid < TPB)
        out_enc[(size_t)(n0 + tid) * KCODES + s_idx[tid]] = 1.0f;

    const size_t qbase = (size_t)n0 * DIM;
    #pragma unroll 4
    for (int i2 = 0; i2 < 32; i2++) {
        int p = i2 * 256 + tid;
        int r = p >> 6, c = p & 63;
        int k = s_idx[r];
        out_q[qbase + p] = w[(size_t)k * DIM + c];
    }
}

// ---------------- rescan: fp64 exact argmin for near-tie tokens; patch outputs
__global__ __launch_bounds__(64) void vq_rescan(
    const float* __restrict__ inputs, const float* __restrict__ w,
    const double* __restrict__ inv_n64, const int* __restrict__ g_idx,
    const int* __restrict__ flags, const int* __restrict__ nflag,
    int* __restrict__ count, float* __restrict__ out_q,
    float* __restrict__ out_enc, double* __restrict__ delta)
{
    __shared__ double sz[64];
    int lane = threadIdx.x;
    int nf = nflag[0];
    for (int i = blockIdx.x; i < nf; i += gridDim.x) {
        int tok = flags[i];
        double zd = (double)inputs[(size_t)tok * DIM + lane];
        double ss = zd * zd;
        #pragma unroll
        for (int off = 32; off; off >>= 1) ss += __shfl_xor(ss, off);
        sz[lane] = zd / fmax(sqrt(ss), 1e-12);
        __syncthreads();
        double bv = -1e300; int bi = 0x7fffffff;
        for (int c = 0; c < 16; c++) {
            int k = c * 64 + lane;
            double invk = inv_n64[k];
            double dot = 0.0;
            #pragma unroll 8
            for (int d = 0; d < DIM; d++)
                dot += sz[d] * ((double)w[(size_t)k * DIM + d] * invk);
            if (dot > bv) { bv = dot; bi = k; }
        }
        #pragma unroll
        for (int off = 1; off < 64; off <<= 1) {
            double ov = __shfl_xor(bv, off);
            int   oi = __shfl_xor(bi, off);
            if (ov > bv || (ov == bv && oi < bi)) { bv = ov; bi = oi; }
        }
        int kold = g_idx[tok];
        if (bi != kold) {
            double wn = (double)w[(size_t)bi * DIM + lane];
            double wo = (double)w[(size_t)kold * DIM + lane];
            double zr = (double)inputs[(size_t)tok * DIM + lane];
            double a = wn * wn - wo * wo - 2.0 * zr * (wn - wo);
            #pragma unroll
            for (int off = 32; off; off >>= 1) a += __shfl_xor(a, off);
            out_q[(size_t)tok * DIM + lane] = (float)wn;
            if (lane == 0) {
                atomicAdd(&count[kold], -1);
                atomicAdd(&count[bi], 1);
                out_enc[(size_t)tok * KCODES + kold] = 0.f;
                out_enc[(size_t)tok * KCODES + bi]   = 1.f;
                atomicAdd(delta, a);
            }
        }
        __syncthreads();
    }
}

// ---------------- finalize: loss scalar + perplexity
__global__ __launch_bounds__(256) void vq_final(
    const int* __restrict__ count, const double* __restrict__ partial,
    const double* __restrict__ delta, float* __restrict__ out_loss,
    float* __restrict__ out_perp)
{
    __shared__ double s1[256], s2[256];
    int tid = threadIdx.x;
    double lp = 0.0, ls = 0.0;
    for (int k = tid; k < KCODES; k += 256) {
        double p = (double)count[k] / (double)N_TOK;
        lp += p * log(p + 1e-10);
    }
    for (int i = tid; i < 1024; i += 256) ls += partial[i];
    s1[tid] = lp; s2[tid] = ls;
    __syncthreads();
    for (int st = 128; st; st >>= 1) {
        if (tid < st) { s1[tid] += s1[tid + st]; s2[tid] += s2[tid + st]; }
        __syncthreads();
    }
    if (tid == 0) {
        out_perp[0] = (float)exp(-s1[0]);
        out_loss[0] = (float)(1.25 * (s2[0] + delta[0]) / ((double)N_TOK * (double)DIM));
    }
}

extern "C" void kernel_launch(void* const* d_in, const int* in_sizes, int n_in,
                              void* d_out, int out_size, void* d_ws, size_t ws_size,
                              hipStream_t stream) {
    const float* inputs = (const float*)d_in[0];
    const float* weight = (const float*)d_in[1];
    float* out      = (float*)d_out;
    float* out_loss = out;                               // [1]
    float* out_q    = out + 1;                           // [N*D]
    float* out_perp = out + 1 + (size_t)N_TOK * DIM;     // [1]
    float* out_enc  = out_perp + 1;                      // [N*K], 8B-aligned

    char* ws = (char*)d_ws;
    unsigned short* bfrag_hi = (unsigned short*)ws;                  // 131072 B
    unsigned short* bfrag_lo = (unsigned short*)(ws + 131072);       // 131072 B
    double* inv_n64 = (double*)(ws + 262144);                        // 8192 B
    float*  nw      = (float*)(ws + 270336);                         // 4096 B
    int*    g_idx   = (int*)(ws + 274432);                           // 524288 B
    int*    count   = (int*)(ws + 798720);                           // 4096 B
    double* partial = (double*)(ws + 802816);                        // 8192 B
    double* delta   = (double*)(ws + 811008);                        // 8 B
    int*    nflag   = (int*)(ws + 811016);                           // 4 B
    int*    flags   = (int*)(ws + 811020);                           // 524288 B

    vq_prep<<<KCODES, 64, 0, stream>>>(weight, bfrag_hi, bfrag_lo, inv_n64, nw,
                                       count, nflag, delta);
    vq_main<<<N_TOK / TPB, 256, 0, stream>>>(inputs, weight, bfrag_hi, bfrag_lo, nw,
                                             g_idx, count, partial, nflag, flags,
                                             out_q, out_enc);
    vq_rescan<<<256, 64, 0, stream>>>(inputs, weight, inv_n64, g_idx, flags, nflag,
                                      count, out_q, out_enc, delta);
    vq_final<<<1, 256, 0, stream>>>(count, partial, delta, out_loss, out_perp);
}